// Round 10
// baseline (250.067 us; speedup 1.0000x reference)
//
#include <hip/hip_runtime.h>
#include <stdint.h>

#define N_NODES 50000
#define N_PAD   50048     // 391 * 128
#define F_IN 512
#define H_DIM 256
#define C_DIM 16
#define G1_BLOCKS (N_PAD / 128)   // 391 gemm tiles

typedef __attribute__((ext_vector_type(8))) short short8;
typedef __attribute__((ext_vector_type(4))) float f32x4;
typedef __attribute__((ext_vector_type(4))) unsigned short us4;
typedef __attribute__((ext_vector_type(8))) unsigned short us8;

__device__ inline float bf2f(unsigned short u) {
    return __uint_as_float(((uint32_t)u) << 16);
}
__device__ inline unsigned short f2bf(float f) {
    uint32_t u = __float_as_uint(f);
    u += 0x7FFFu + ((u >> 16) & 1u);   // round-to-nearest-even
    return (unsigned short)(u >> 16);
}
__device__ inline unsigned short hx(float f) {   // truncating bf16 (1 op)
    return (unsigned short)(__float_as_uint(f) >> 16);
}
__device__ inline int eidx(const void* p, long long i, int is64) {
    return is64 ? (int)((const long long*)p)[i] : ((const int*)p)[i];
}

// CSR row bounds: rowoff = per-512-chunk exclusive sums, bsum = scanned
// chunk offsets (scanned in-place by scan1's last block).
__device__ inline int row_beg(const int* ro, const int* bs, int n) {
    return ro[n] + bs[n >> 9];
}
__device__ inline int row_end(const int* ro, const int* bs, int n, int E) {
    return (n + 1 < N_NODES) ? ro[n + 1] + bs[(n + 1) >> 9] : E;
}

// async global->LDS, 16B per lane, linear LDS dest (wave base + lane*16)
#define GLOAD16(gp, lp)                                                       \
    __builtin_amdgcn_global_load_lds(                                         \
        (const __attribute__((address_space(1))) void*)(gp),                  \
        (__attribute__((address_space(3))) void*)(lp), 16, 0, 0)

// ---------- fused prep: detect + W transpose-convert + zero cnt/cur/done ---

__global__ void prep_k(const void* ei, int* flag,
                       const float* w1, unsigned short* w1t,
                       const float* w2, unsigned short* w2t,
                       int* cnt, int* cur, int* done) {
    int i = blockIdx.x * 256 + threadIdx.x;
    if (i == 0) {
        const uint32_t* w = (const uint32_t*)ei;
        int is64 = 1;
        for (int j = 1; j < 128; j += 2)
            if (w[j] != 0u) { is64 = 0; break; }
        *flag = is64;
        *done = 0;
    }
    if (i < N_NODES) { cnt[i] = 0; cur[i] = 0; }
    if (i < F_IN * H_DIM) {
        int k = i / H_DIM, n = i % H_DIM;
        w1t[n * F_IN + k] = f2bf(w1[i]);
    }
    if (i < H_DIM * C_DIM) {
        int k = i / C_DIM, n = i % C_DIM;
        w2t[n * H_DIM + k] = f2bf(w2[i]);
    }
}

// ---------- graph build ----------

__global__ void hist_k(const void* ei, const int* flag, int* cnt, long long E) {
    long long e = (long long)blockIdx.x * 256 + threadIdx.x;
    if (e >= E) return;
    int d = eidx(ei, E + e, *flag);
    atomicAdd(&cnt[d], 1);
}

// per-chunk scan; the LAST block to finish additionally scans bsum in place
// (rocPRIM-style done-counter; deterministic: one thread, sequential).
__global__ __launch_bounds__(512) void scan1_k(const int* cnt, int* rowoff, int* bsum,
                                               float* dinv, int* done, int n, int nblk) {
    __shared__ int s[512];
    __shared__ int amLast;
    int t = threadIdx.x;
    int i = blockIdx.x * 512 + t;
    int v = (i < n) ? cnt[i] : 0;
    s[t] = v;
    __syncthreads();
    for (int off = 1; off < 512; off <<= 1) {
        int add = (t >= off) ? s[t - off] : 0;
        __syncthreads();
        s[t] += add;
        __syncthreads();
    }
    if (i < n) {
        rowoff[i] = s[t] - v;                 // exclusive within chunk
        dinv[i] = rsqrtf((float)(v + 1));     // +1 self loop
    }
    if (t == 511) bsum[blockIdx.x] = s[511];
    __threadfence();                           // publish bsum write
    if (t == 0) amLast = (atomicAdd(done, 1) == nblk - 1);
    __syncthreads();
    if (amLast && t == 0) {
        __threadfence();                       // acquire all bsum writes
        volatile int* vb = bsum;
        int run = 0;
        for (int b = 0; b < nblk; ++b) {
            int x = vb[b];
            vb[b] = run;
            run += x;
        }
    }
}

// ---------- fused GEMM1 + scatter (independent work, one dispatch) ---------
// blocks [0, G1_BLOCKS): h1 = bf16(x @ W1) — fp32-A gload_lds, counted-vmcnt
//   pipeline (r9 structure, unchanged).
// blocks [G1_BLOCKS, ...): CSR scatter of (src, norm) pairs — hides under
//   the GEMM (mutually independent: scatter needs graph chain, gemm needs
//   only x/W1).

__global__ __launch_bounds__(512, 4) void gemm1scat_k(
        const float* __restrict__ x, const unsigned short* __restrict__ w1t,
        unsigned short* __restrict__ h1,
        const void* __restrict__ ei, const int* __restrict__ flag,
        const float* __restrict__ dinv, const int* __restrict__ rowoff,
        const int* __restrict__ bsum, int* __restrict__ cur,
        long long E, int2* __restrict__ colnorm) {
    __shared__ __align__(16) float          Asf[2][128 * 32];  // 32 KB
    __shared__ __align__(16) unsigned short Bs[2][256 * 32];   // 32 KB

    if (blockIdx.x >= G1_BLOCKS) {
        // ---- scatter role ----
        long long e = (long long)(blockIdx.x - G1_BLOCKS) * 512 + threadIdx.x;
        if (e < E) {
            int is64 = *flag;
            int s = eidx(ei, e, is64);
            int d = eidx(ei, E + e, is64);
            int pos = row_beg(rowoff, bsum, d) + atomicAdd(&cur[d], 1);
            float nrm = dinv[s] * dinv[d];
            int2 cn;
            cn.x = s;
            cn.y = __float_as_int(nrm);
            colnorm[pos] = cn;
        }
        return;
    }

    // ---- gemm role (identical to r9) ----
    const int t = threadIdx.x;
    const int wv = t >> 6, lane = t & 63;
    const int lg = lane >> 4, lr = lane & 15;
    const int wm = wv >> 2, wn = wv & 3;

    const int arow0 = t >> 3;
    const int achk = (t & 7) ^ (arow0 & 7);
    size_t g0 = (size_t)blockIdx.x * 128 + arow0;
    size_t g1 = g0 + 64;
    if (g0 > N_NODES - 1) g0 = N_NODES - 1;
    if (g1 > N_NODES - 1) g1 = N_NODES - 1;
    const float* asrc0 = x + g0 * F_IN + achk * 4;
    const float* asrc1 = x + g1 * F_IN + achk * 4;
    const unsigned short* bsrc0 = w1t + (size_t)(t >> 2) * F_IN + (t & 3) * 8;
    const unsigned short* bsrc1 = bsrc0 + 128 * F_IN;

#define STAGE(bf, ks)                                                         \
    do { const int _o = (ks) * 32;                                            \
        GLOAD16(asrc0 + _o, &Asf[bf][t * 4]);                                 \
        GLOAD16(asrc1 + _o, &Asf[bf][t * 4 + 2048]);                          \
        GLOAD16(bsrc0 + _o, &Bs[bf][t * 8]);                                  \
        GLOAD16(bsrc1 + _o, &Bs[bf][(t + 512) * 8]);                          \
    } while (0)

    f32x4 acc[4][4] = {};

    STAGE(0, 0);                       // 4 outstanding

    for (int ks = 0; ks < 16; ++ks) {
        const int bf = ks & 1;
        if (ks < 15) {
            STAGE(bf ^ 1, ks + 1);     // <=8 outstanding
            asm volatile("s_waitcnt vmcnt(4)" ::: "memory");  // buf-ks landed
        } else {
            asm volatile("s_waitcnt vmcnt(0)" ::: "memory");
        }
        __builtin_amdgcn_sched_barrier(0);
        __builtin_amdgcn_s_barrier();  // bar1: buf-ks visible to all waves

        short8 afr[4], bfr[4];
#pragma unroll
        for (int mi = 0; mi < 4; ++mi) {
            const int r = wm * 64 + mi * 16 + lr;
            const int s = r & 7;
            const float* base = &Asf[bf][r * 32];
            f32x4 lo = *(const f32x4*)(base + (((lg * 2) ^ s) * 4));
            f32x4 hi = *(const f32x4*)(base + (((lg * 2 + 1) ^ s) * 4));
            short8 a;
            a[0] = (short)hx(lo[0]); a[1] = (short)hx(lo[1]);
            a[2] = (short)hx(lo[2]); a[3] = (short)hx(lo[3]);
            a[4] = (short)hx(hi[0]); a[5] = (short)hx(hi[1]);
            a[6] = (short)hx(hi[2]); a[7] = (short)hx(hi[3]);
            afr[mi] = a;
        }
#pragma unroll
        for (int ni = 0; ni < 4; ++ni)
            bfr[ni] = *(const short8*)&Bs[bf][(wn * 64 + ni * 16 + lr) * 32 + lg * 8];
#pragma unroll
        for (int mi = 0; mi < 4; ++mi)
#pragma unroll
            for (int ni = 0; ni < 4; ++ni)
                acc[mi][ni] = __builtin_amdgcn_mfma_f32_16x16x32_bf16(
                    afr[mi], bfr[ni], acc[mi][ni], 0, 0, 0);

        asm volatile("s_waitcnt lgkmcnt(0)" ::: "memory");
        __builtin_amdgcn_sched_barrier(0);
        __builtin_amdgcn_s_barrier();  // bar2: safe to overwrite next buffer
    }
#undef STAGE

    const size_t rbase = (size_t)blockIdx.x * 128 + wm * 64 + lg * 4;
#pragma unroll
    for (int mi = 0; mi < 4; ++mi)
#pragma unroll
        for (int ni = 0; ni < 4; ++ni)
#pragma unroll
            for (int j = 0; j < 4; ++j)
                h1[(rbase + mi * 16 + j) * H_DIM + wn * 64 + ni * 16 + lr] =
                    f2bf(acc[mi][ni][j]);
}

// ---------- Aggregation layer 1: h1a = bf16(relu(Anorm@h1+b1)) -------------

__global__ __launch_bounds__(256) void agg1_k(const unsigned short* __restrict__ h1,
                                              const int* __restrict__ rowoff,
                                              const int* __restrict__ bsum,
                                              const int2* __restrict__ colnorm,
                                              const float* __restrict__ dinv,
                                              const float* __restrict__ b1,
                                              unsigned short* __restrict__ h1a,
                                              int E) {
    int wv = threadIdx.x >> 6, lane = threadIdx.x & 63;
    int node = blockIdx.x * 4 + wv;
    if (node >= N_NODES) return;
    int half = lane >> 5;
    int fl = (lane & 31) * 8;
    int beg = row_beg(rowoff, bsum, node);
    int end = row_end(rowoff, bsum, node, E);
    float a[8] = {0.f, 0.f, 0.f, 0.f, 0.f, 0.f, 0.f, 0.f};
    const unsigned short* base = h1 + fl;

    int e = beg + half;
    while (e + 6 < end) {
        int2 c[4];
        us8 v[4];
#pragma unroll
        for (int q = 0; q < 4; ++q) c[q] = colnorm[e + q * 2];
#pragma unroll
        for (int q = 0; q < 4; ++q)
            v[q] = *(const us8*)(base + (long long)c[q].x * H_DIM);
#pragma unroll
        for (int q = 0; q < 4; ++q) {
            float n = __int_as_float(c[q].y);
#pragma unroll
            for (int j = 0; j < 8; ++j) a[j] += n * bf2f(v[q][j]);
        }
        e += 8;
    }
    while (e < end) {
        int2 c0 = colnorm[e];
        us8 v0 = *(const us8*)(base + (long long)c0.x * H_DIM);
        float n0 = __int_as_float(c0.y);
#pragma unroll
        for (int j = 0; j < 8; ++j) a[j] += n0 * bf2f(v0[j]);
        e += 2;
    }
#pragma unroll
    for (int j = 0; j < 8; ++j)
        a[j] += __shfl_xor(a[j], 32);

    if (half == 0) {
        float dn = dinv[node];
        float sn = dn * dn;
        us8 vs = *(const us8*)(base + (long long)node * H_DIM);
        float4 b0 = *(const float4*)(b1 + fl);
        float4 b4 = *(const float4*)(b1 + fl + 4);
        float bb[8] = {b0.x, b0.y, b0.z, b0.w, b4.x, b4.y, b4.z, b4.w};
        us8 o;
#pragma unroll
        for (int j = 0; j < 8; ++j) {
            float r = fmaxf(a[j] + sn * bf2f(vs[j]) + bb[j], 0.f);
            o[j] = f2bf(r);
        }
        *(us8*)(h1a + (long long)node * H_DIM + fl) = o;
    }
}

// ---------- GEMM2: h2[50000x16] = h1a @ W2 (MFMA straight from global) ----

__global__ __launch_bounds__(256) void gemm2_k(const unsigned short* __restrict__ h1a,
                                               const unsigned short* __restrict__ w2t,
                                               float* __restrict__ h2) {
    int t = threadIdx.x;
    int wv = t >> 6, lane = t & 63, lg = lane >> 4, lr = lane & 15;
    int rbase = blockIdx.x * 64 + wv * 16;
    int rr = rbase + lr;
    int rc = rr < N_NODES ? rr : N_NODES - 1;
    f32x4 acc = {0.f, 0.f, 0.f, 0.f};
#pragma unroll
    for (int ks = 0; ks < 8; ++ks) {
        short8 a = *(const short8*)(h1a + (long long)rc * H_DIM + ks * 32 + lg * 8);
        short8 b = *(const short8*)(w2t + lr * H_DIM + ks * 32 + lg * 8);
        acc = __builtin_amdgcn_mfma_f32_16x16x32_bf16(a, b, acc, 0, 0, 0);
    }
#pragma unroll
    for (int j = 0; j < 4; ++j) {
        int row = rbase + lg * 4 + j;
        if (row < N_NODES) h2[(long long)row * C_DIM + lr] = acc[j];
    }
}

// ---------- Aggregation layer 2: out = A_norm @ h2 + b2 (fp32) ----------

__global__ __launch_bounds__(256) void agg2_k(const float* __restrict__ h2,
                                              const int* __restrict__ rowoff,
                                              const int* __restrict__ bsum,
                                              const int2* __restrict__ colnorm,
                                              const float* __restrict__ dinv,
                                              const float* __restrict__ b2,
                                              float* __restrict__ out, int E) {
    int g = threadIdx.x >> 4, c = threadIdx.x & 15;
    int node = blockIdx.x * 16 + g;
    if (node >= N_NODES) return;
    int beg = row_beg(rowoff, bsum, node);
    int end = row_end(rowoff, bsum, node, E);
    float acc = 0.f;
    int e = beg;
    for (; e + 3 < end; e += 4) {
        int2 cn0 = colnorm[e];
        int2 cn1 = colnorm[e + 1];
        int2 cn2 = colnorm[e + 2];
        int2 cn3 = colnorm[e + 3];
        float v0 = h2[(long long)cn0.x * C_DIM + c];
        float v1 = h2[(long long)cn1.x * C_DIM + c];
        float v2 = h2[(long long)cn2.x * C_DIM + c];
        float v3 = h2[(long long)cn3.x * C_DIM + c];
        acc += __int_as_float(cn0.y) * v0 + __int_as_float(cn1.y) * v1
             + __int_as_float(cn2.y) * v2 + __int_as_float(cn3.y) * v3;
    }
    for (; e < end; ++e) {
        int2 cn = colnorm[e];
        acc += __int_as_float(cn.y) * h2[(long long)cn.x * C_DIM + c];
    }
    float dn = dinv[node];
    acc += dn * dn * h2[(long long)node * C_DIM + c];
    out[(long long)node * C_DIM + c] = acc + b2[c];
}

// ---------- launch ----------

extern "C" void kernel_launch(void* const* d_in, const int* in_sizes, int n_in,
                              void* d_out, int out_size, void* d_ws, size_t ws_size,
                              hipStream_t stream) {
    const float* x  = (const float*)d_in[0];
    const void*  ei = d_in[1];
    const float* W1 = (const float*)d_in[2];
    const float* b1 = (const float*)d_in[3];
    const float* W2 = (const float*)d_in[4];
    const float* b2 = (const float*)d_in[5];
    float* out = (float*)d_out;
    long long E = (long long)in_sizes[1] / 2;

    char* w = (char*)d_ws;
    auto alloc = [&](size_t bytes) -> char* {
        char* p = w;
        w += (bytes + 255) & ~(size_t)255;
        return p;
    };
    int*   flag    = (int*)   alloc(8);        // flag + done
    int*   done    = flag + 1;
    int*   cnt     = (int*)   alloc((size_t)N_NODES * 4);
    int*   cur     = (int*)   alloc((size_t)N_NODES * 4);
    float* dinv    = (float*) alloc((size_t)N_NODES * 4);
    int*   rowoff  = (int*)   alloc((size_t)N_NODES * 4);
    int*   bsum    = (int*)   alloc(512 * 4);
    int2*  colnorm = (int2*)  alloc((size_t)E * 8);
    unsigned short* w1t = (unsigned short*)alloc((size_t)H_DIM * F_IN * 2);
    unsigned short* w2t = (unsigned short*)alloc((size_t)C_DIM * H_DIM * 2);
    unsigned short* h1  = (unsigned short*)alloc((size_t)N_PAD * H_DIM * 2);   // 25.6 MB
    unsigned short* h1a = (unsigned short*)alloc((size_t)N_NODES * H_DIM * 2); // 25.6 MB
    float* h2 = (float*)alloc((size_t)N_NODES * C_DIM * 4);

    prep_k<<<(F_IN * H_DIM + 255) / 256, 256, 0, stream>>>(ei, flag, W1, w1t, W2, w2t,
                                                           cnt, cur, done);

    int egrid = (int)((E + 255) / 256);
    hist_k<<<egrid, 256, 0, stream>>>(ei, flag, cnt, E);
    int sgrid = (N_NODES + 511) / 512;   // 98
    scan1_k<<<sgrid, 512, 0, stream>>>(cnt, rowoff, bsum, dinv, done, N_NODES, sgrid);

    int scgrid = (int)((E + 511) / 512);             // 1563 scatter blocks
    gemm1scat_k<<<G1_BLOCKS + scgrid, 512, 0, stream>>>(
        x, w1t, h1, ei, flag, dinv, rowoff, bsum, cur, E, colnorm);

    agg1_k<<<(N_NODES + 3) / 4, 256, 0, stream>>>(h1, rowoff, bsum, colnorm, dinv,
                                                  b1, h1a, (int)E);
    gemm2_k<<<(N_NODES + 63) / 64, 256, 0, stream>>>(h1a, w2t, h2);
    agg2_k<<<(N_NODES + 15) / 16, 256, 0, stream>>>(h2, rowoff, bsum, colnorm, dinv,
                                                    b2, out, (int)E);
}